// Round 1
// baseline (723.938 us; speedup 1.0000x reference)
//
#include <hip/hip_runtime.h>
#include <cstddef>

#define TT 1024
#define BB 512
#define DD 128
#define FAN 136   // D + H

// ---------- fast transcendental helpers (raw gfx950 VOP1, safe names) ----------
__device__ __forceinline__ float v_exp2(float x){ float d; asm("v_exp_f32 %0, %1" : "=v"(d) : "v"(x)); return d; }
__device__ __forceinline__ float v_rcp (float x){ float d; asm("v_rcp_f32 %0, %1" : "=v"(d) : "v"(x)); return d; }
__device__ __forceinline__ float v_cosr(float x){ float d; asm("v_cos_f32 %0, %1" : "=v"(d) : "v"(x)); return d; }

__device__ __forceinline__ float fast_cos(float x){
    // v_cos takes revolutions; reduce with fract (valid for any sign)
    float r = x * 0.15915494309189535f;
    r = r - floorf(r);
    return v_cosr(r);
}
__device__ __forceinline__ float fast_sigmoid(float x){
    float e = v_exp2(x * -1.4426950408889634f);   // 2^(-x*log2e) = e^-x
    return v_rcp(1.0f + e);
}
__device__ __forceinline__ float fast_tanh(float x){
    float e = v_exp2(x * 2.8853900817779268f);    // e^(2x)
    return 1.0f - 2.0f * v_rcp(e + 1.0f);         // handles +-inf gracefully
}

// ---------------------------------------------------------------------------
// K1: Zx[t][k][b], k = 0..7 -> Wu rows (+bu), 8/9/10 -> Wf/Wi/Wo row 0 (+bias).
// x-part of all gate pre-activations. One thread per (t,b); x staged in LDS.
// ---------------------------------------------------------------------------
__global__ __launch_bounds__(256) void qlstm_zx(
    const float* __restrict__ x,    // [T][B][D]
    const float* __restrict__ Wf, const float* __restrict__ bf,
    const float* __restrict__ Wi, const float* __restrict__ bi,
    const float* __restrict__ Wu, const float* __restrict__ bu,
    const float* __restrict__ Wo, const float* __restrict__ bo,
    float* __restrict__ Z)          // [T][12][B]
{
    __shared__ float xs[256 * 33];          // [256 rows][32 cols] padded to 33
    const int tid = threadIdx.x;
    const int t  = blockIdx.x >> 1;
    const int b0 = (blockIdx.x & 1) * 256;

    float acc[8];
    #pragma unroll
    for (int k = 0; k < 8; ++k) acc[k] = bu[k];
    float af = bf[0], ai = bi[0], ao = bo[0];

    const float* xbase = x + ((size_t)t * BB + b0) * DD;

    for (int dc = 0; dc < 4; ++dc) {
        // cooperative coalesced load of x[t, b0:b0+256, dc*32:(dc+1)*32]
        #pragma unroll
        for (int i = 0; i < 8; ++i) {
            int idx = i * 256 + tid;
            int row = idx >> 3, cg = idx & 7;
            const float4 v = *reinterpret_cast<const float4*>(xbase + row * DD + dc * 32 + cg * 4);
            float* d = &xs[row * 33 + cg * 4];
            d[0] = v.x; d[1] = v.y; d[2] = v.z; d[3] = v.w;
        }
        __syncthreads();

        const int base = dc * 32;
        #pragma unroll
        for (int d = 0; d < 32; ++d) {
            const float xv = xs[tid * 33 + d];  // conflict-free (2-way, free)
            const int wc = base + d;            // wave-uniform -> s_load
            #pragma unroll
            for (int k = 0; k < 8; ++k) acc[k] = fmaf(xv, Wu[k * FAN + wc], acc[k]);
            af = fmaf(xv, Wf[wc], af);
            ai = fmaf(xv, Wi[wc], ai);
            ao = fmaf(xv, Wo[wc], ao);
        }
        __syncthreads();
    }

    float* zb = Z + (size_t)t * 12 * BB + b0 + tid;   // coalesced stores
    #pragma unroll
    for (int k = 0; k < 8; ++k) zb[k * BB] = acc[k];
    zb[8 * BB] = af; zb[9 * BB] = ai; zb[10 * BB] = ao;
}

// ---------------------------------------------------------------------------
// K2: sequential recurrence. 64 blocks x 64 threads; 8 chains per wave,
// 8 lanes per chain. Lane (g,j) owns h[j],c[j] of chain b = bid*8+g and keeps
// a replicated copy of the full hx[0..7] (a[m] = hx[j^m]) with XOR-permuted
// weight copies, rebuilt each step with 7 shfl_xor — no divergence, no LDS.
// ---------------------------------------------------------------------------
__global__ __launch_bounds__(64) void qlstm_rec(
    const float* __restrict__ Z,    // [T][12][B]
    const float* __restrict__ Wf, const float* __restrict__ Wi,
    const float* __restrict__ Wu, const float* __restrict__ Wo,
    const float* __restrict__ qwf, const float* __restrict__ qwi,
    const float* __restrict__ qwo,
    float* __restrict__ out)        // outputs [T][B][8] ++ hx [B][8] ++ cx [B][8]
{
    const int l = threadIdx.x;
    const int g = l >> 3, j = l & 7;
    const int b = blockIdx.x * 8 + g;

    // XOR-permuted recurrent weights: w_[m] pairs with a[m] = hx[j^m]
    float wu_[8], wf_[8], wi_[8], wo_[8];
    #pragma unroll
    for (int m = 0; m < 8; ++m) {
        const int k = j ^ m;
        wu_[m] = Wu[j * FAN + 128 + k];
        wf_[m] = Wf[128 + k];
        wi_[m] = Wi[128 + k];
        wo_[m] = Wo[128 + k];
    }
    const float cqf = cosf(qwf[0]);
    const float cqi = cosf(qwi[0]);
    const float cqo = cosf(qwo[0]);

    float a[8];
    #pragma unroll
    for (int m = 0; m < 8; ++m) a[m] = 0.f;
    float c = 0.f;

    // prefetch registers for step t
    const float* z0 = Z + b;
    float zu = z0[(size_t)j * BB];
    float zf = z0[8 * BB], zi = z0[9 * BB], zo = z0[10 * BB];

    const int obase = blockIdx.x * 64 + l;

    for (int t = 0; t < TT; ++t) {
        // prefetch t+1 (hidden under compute)
        float nzu = 0.f, nzf = 0.f, nzi = 0.f, nzo = 0.f;
        if (t + 1 < TT) {
            const float* zn = Z + (size_t)(t + 1) * 12 * BB + b;
            nzu = zn[(size_t)j * BB];
            nzf = zn[8 * BB]; nzi = zn[9 * BB]; nzo = zn[10 * BB];
        }

        // 4 dots of length 8, all operands lane-local
        float du = zu, df = zf, di = zi, dq = zo;
        #pragma unroll
        for (int m = 0; m < 8; ++m) {
            du = fmaf(a[m], wu_[m], du);
            df = fmaf(a[m], wf_[m], df);
            di = fmaf(a[m], wi_[m], di);
            dq = fmaf(a[m], wo_[m], dq);
        }

        const float f  = fast_sigmoid(fast_cos(df) * cqf);
        const float i_ = fast_sigmoid(fast_cos(di) * cqi);
        const float o_ = fast_sigmoid(fast_cos(dq) * cqo);
        const float gg = fast_tanh(du);

        c = fmaf(f, c, i_ * gg);
        const float h = o_ * fast_tanh(c);

        out[(size_t)t * 4096 + obase] = h;   // contiguous 256B per wave

        // allgather new hx within the 8-lane group (7 shuffles)
        a[0] = h;
        a[1] = __shfl_xor(a[0], 1);
        a[2] = __shfl_xor(a[0], 2);
        a[3] = __shfl_xor(a[1], 2);
        a[4] = __shfl_xor(a[0], 4);
        a[5] = __shfl_xor(a[1], 4);
        a[6] = __shfl_xor(a[2], 4);
        a[7] = __shfl_xor(a[3], 4);

        zu = nzu; zf = nzf; zi = nzi; zo = nzo;
    }

    // final hx, cx
    out[4194304 + obase] = a[0];
    out[4198400 + obase] = c;
}

// ---------------------------------------------------------------------------
extern "C" void kernel_launch(void* const* d_in, const int* in_sizes, int n_in,
                              void* d_out, int out_size, void* d_ws, size_t ws_size,
                              hipStream_t stream) {
    const float* x   = (const float*)d_in[0];
    const float* Wf  = (const float*)d_in[1];
    const float* bf  = (const float*)d_in[2];
    const float* Wi  = (const float*)d_in[3];
    const float* bi  = (const float*)d_in[4];
    const float* Wu  = (const float*)d_in[5];
    const float* bu  = (const float*)d_in[6];
    const float* Wo  = (const float*)d_in[7];
    const float* bo  = (const float*)d_in[8];
    const float* qwf = (const float*)d_in[9];
    const float* qwi = (const float*)d_in[10];
    // d_in[11] = qwu (unused by reference: g-gate has no quantum circuit)
    const float* qwo = (const float*)d_in[12];
    float* out = (float*)d_out;
    float* Z   = (float*)d_ws;      // needs 1024*12*512*4 = 25.2 MB

    qlstm_zx<<<2048, 256, 0, stream>>>(x, Wf, bf, Wi, bi, Wu, bu, Wo, bo, Z);
    qlstm_rec<<<64, 64, 0, stream>>>(Z, Wf, Wi, Wu, Wo, qwf, qwi, qwo, out);
}

// Round 2
// 594.291 us; speedup vs baseline: 1.2182x; 1.2182x over previous
//
#include <hip/hip_runtime.h>
#include <cstddef>

#define TT 1024
#define BB 512
#define FAN 136   // D + H

// ---------- fast transcendentals (raw gfx950 VOP1) ----------
__device__ __forceinline__ float v_exp2 (float x){ float d; asm("v_exp_f32 %0, %1"   : "=v"(d) : "v"(x)); return d; }
__device__ __forceinline__ float v_rcp  (float x){ float d; asm("v_rcp_f32 %0, %1"   : "=v"(d) : "v"(x)); return d; }
__device__ __forceinline__ float v_cosr (float x){ float d; asm("v_cos_f32 %0, %1"   : "=v"(d) : "v"(x)); return d; }
__device__ __forceinline__ float v_fract(float x){ float d; asm("v_fract_f32 %0, %1" : "=v"(d) : "v"(x)); return d; }

__device__ __forceinline__ float fast_cos(float x){
    return v_cosr(v_fract(x * 0.15915494309189535f));   // v_cos takes revolutions
}
__device__ __forceinline__ float fast_sigmoid(float x){
    return v_rcp(1.0f + v_exp2(x * -1.4426950408889634f));
}
__device__ __forceinline__ float fast_tanh(float x){
    return 1.0f - 2.0f * v_rcp(v_exp2(x * 2.8853900817779268f) + 1.0f);
}

// ---------- cross-lane helpers ----------
// DPP: xor1=quad_perm[1,0,3,2]=0xB1, xor2=0x4E, xor3=0x1B, xor7=row_half_mirror=0x141
template<int CTRL>
__device__ __forceinline__ float dppf(float x){
    return __int_as_float(__builtin_amdgcn_mov_dpp(__float_as_int(x), CTRL, 0xF, 0xF, true));
}
// ds_swizzle BitMode: offset = (xor<<10) | 0x1F
template<int PAT>
__device__ __forceinline__ float swzf(float x){
    return __int_as_float(__builtin_amdgcn_ds_swizzle(__float_as_int(x), PAT));
}

// ---------------------------------------------------------------------------
// K1: x-part of gate pre-activations (+bias), written as Z[t][b/8][k*8 + b%8],
// row-padded to 96 floats per octet (k=0..10 used; 88..95 never read).
// Thread = (batch row, d-slice of 8). Weights live in 88 VGPRs. No LDS.
// ---------------------------------------------------------------------------
__global__ __launch_bounds__(256) void qlstm_zx2(
    const float* __restrict__ x,    // [T][B][128]
    const float* __restrict__ Wf, const float* __restrict__ bf,
    const float* __restrict__ Wi, const float* __restrict__ bi,
    const float* __restrict__ Wu, const float* __restrict__ bu,
    const float* __restrict__ Wo, const float* __restrict__ bo,
    float* __restrict__ Z)          // [T][64][96]
{
    const int tid = threadIdx.x;
    const int bl  = tid >> 4;       // batch lane within 16-row group
    const int ds  = tid & 15;       // d-slice: covers d = ds*8 .. ds*8+7
    const int t   = blockIdx.x >> 1;
    const int b0  = (blockIdx.x & 1) * 256;

    // weight slice in registers: rows 0..7 = Wu rows, 8=Wf0, 9=Wi0, 10=Wo0
    float w[11][8];
    #pragma unroll
    for (int k = 0; k < 8; ++k) {
        const float4 lo = *reinterpret_cast<const float4*>(Wu + k * FAN + ds * 8);
        const float4 hi = *reinterpret_cast<const float4*>(Wu + k * FAN + ds * 8 + 4);
        w[k][0]=lo.x; w[k][1]=lo.y; w[k][2]=lo.z; w[k][3]=lo.w;
        w[k][4]=hi.x; w[k][5]=hi.y; w[k][6]=hi.z; w[k][7]=hi.w;
    }
    {
        const float4 lo = *reinterpret_cast<const float4*>(Wf + ds * 8);
        const float4 hi = *reinterpret_cast<const float4*>(Wf + ds * 8 + 4);
        w[8][0]=lo.x; w[8][1]=lo.y; w[8][2]=lo.z; w[8][3]=lo.w;
        w[8][4]=hi.x; w[8][5]=hi.y; w[8][6]=hi.z; w[8][7]=hi.w;
    }
    {
        const float4 lo = *reinterpret_cast<const float4*>(Wi + ds * 8);
        const float4 hi = *reinterpret_cast<const float4*>(Wi + ds * 8 + 4);
        w[9][0]=lo.x; w[9][1]=lo.y; w[9][2]=lo.z; w[9][3]=lo.w;
        w[9][4]=hi.x; w[9][5]=hi.y; w[9][6]=hi.z; w[9][7]=hi.w;
    }
    {
        const float4 lo = *reinterpret_cast<const float4*>(Wo + ds * 8);
        const float4 hi = *reinterpret_cast<const float4*>(Wo + ds * 8 + 4);
        w[10][0]=lo.x; w[10][1]=lo.y; w[10][2]=lo.z; w[10][3]=lo.w;
        w[10][4]=hi.x; w[10][5]=hi.y; w[10][6]=hi.z; w[10][7]=hi.w;
    }

    float my_bias = 0.f;
    if (ds <  8) my_bias = bu[ds];
    if (ds ==  8) my_bias = bf[0];
    if (ds ==  9) my_bias = bi[0];
    if (ds == 10) my_bias = bo[0];

    const float* xp = x + ((size_t)(t * BB + b0 + bl)) * 128 + ds * 8;

    for (int it = 0; it < 16; ++it) {
        const int b = b0 + it * 16 + bl;
        const float4 xa = *reinterpret_cast<const float4*>(xp);
        const float4 xb = *reinterpret_cast<const float4*>(xp + 4);
        const float xr[8] = {xa.x, xa.y, xa.z, xa.w, xb.x, xb.y, xb.z, xb.w};

        float acc[11];
        #pragma unroll
        for (int k = 0; k < 11; ++k) {
            float s = 0.f;
            #pragma unroll
            for (int e = 0; e < 8; ++e) s = fmaf(xr[e], w[k][e], s);
            acc[k] = s;
        }
        // allreduce over the 16 d-slice lanes (xor 1,2 via DPP; 4,8 via swizzle)
        #pragma unroll
        for (int k = 0; k < 11; ++k) {
            float v = acc[k];
            v += dppf<0xB1>(v);
            v += dppf<0x4E>(v);
            v += swzf<0x101F>(v);
            v += swzf<0x201F>(v);
            acc[k] = v;
        }
        // lane ds writes output row k = ds
        float val = acc[0];
        #pragma unroll
        for (int k = 1; k < 11; ++k) val = (ds == k) ? acc[k] : val;
        val += my_bias;
        if (ds < 11)
            Z[(size_t)t * 6144 + (size_t)(b >> 3) * 96 + ds * 8 + (b & 7)] = val;

        xp += 16 * 128;
    }
}

// ---------------------------------------------------------------------------
// K2: sequential recurrence. 64 blocks x 1 wave; 8 chains/wave, 8 lanes/chain.
// 8-step-deep register prefetch ring hides Z load latency; hx allgather via
// 2-level DPP (VALU, no DS pipe on the critical path).
// ---------------------------------------------------------------------------
__global__ __launch_bounds__(64) void qlstm_rec2(
    const float* __restrict__ Z,    // [T][64][96]
    const float* __restrict__ Wf, const float* __restrict__ Wi,
    const float* __restrict__ Wu, const float* __restrict__ Wo,
    const float* __restrict__ qwf, const float* __restrict__ qwi,
    const float* __restrict__ qwo,
    float* __restrict__ out)        // [T][B][8] ++ hx[B][8] ++ cx[B][8]
{
    const int l = threadIdx.x;
    const int g = l >> 3, j = l & 7;
    const int bid = blockIdx.x;

    // XOR-permuted recurrent weights: w_[m] pairs with a[m] = hx[j^m]
    float wu_[8], wf_[8], wi_[8], wo_[8];
    #pragma unroll
    for (int m = 0; m < 8; ++m) {
        const int k = j ^ m;
        wu_[m] = Wu[j * FAN + 128 + k];
        wf_[m] = Wf[128 + k];
        wi_[m] = Wi[128 + k];
        wo_[m] = Wo[128 + k];
    }
    const float cqf = fast_cos(qwf[0]);
    const float cqi = fast_cos(qwi[0]);
    const float cqo = fast_cos(qwo[0]);

    float a[8];
    #pragma unroll
    for (int m = 0; m < 8; ++m) a[m] = 0.f;
    float c = 0.f, h = 0.f;

    const float* zb = Z + (size_t)bid * 96;
    const int ou = j * 8 + g;       // own g-gate preact
    const int of = 64 + g, oi = 72 + g, oo = 80 + g;

    // prefetch ring, depth 8 (static indices only)
    float zr[8][4];
    #pragma unroll
    for (int p = 0; p < 8; ++p) {
        const float* s = zb + (size_t)p * 6144;
        zr[p][0] = s[ou]; zr[p][1] = s[of]; zr[p][2] = s[oi]; zr[p][3] = s[oo];
    }

    float* op = out + bid * 64 + l;

    for (int t0 = 0; t0 < TT; t0 += 8) {
        #pragma unroll
        for (int p = 0; p < 8; ++p) {
            const float zu = zr[p][0], zf = zr[p][1], zi = zr[p][2], zo = zr[p][3];
            // refill slot p for step t0+p+8 (clamped; tail loads unused)
            {
                const int tn = t0 + p + 8;
                const float* s = zb + (size_t)(tn < TT ? tn : TT - 1) * 6144;
                zr[p][0] = s[ou]; zr[p][1] = s[of]; zr[p][2] = s[oi]; zr[p][3] = s[oo];
            }

            float du = zu, df = zf, di = zi, dq = zo;
            #pragma unroll
            for (int m = 0; m < 8; ++m) {
                du = fmaf(a[m], wu_[m], du);
                df = fmaf(a[m], wf_[m], df);
                di = fmaf(a[m], wi_[m], di);
                dq = fmaf(a[m], wo_[m], dq);
            }

            const float f  = fast_sigmoid(fast_cos(df) * cqf);
            const float i_ = fast_sigmoid(fast_cos(di) * cqi);
            const float o_ = fast_sigmoid(fast_cos(dq) * cqo);
            const float gg = fast_tanh(du);

            c = fmaf(f, c, i_ * gg);
            h = o_ * fast_tanh(c);

            *op = h; op += 4096;

            // allgather h across the 8-lane group: 2 DPP levels, no DS pipe
            a[0] = h;
            a[1] = dppf<0xB1>(h);           // h[j^1]
            a[2] = dppf<0x4E>(h);           // h[j^2]
            a[3] = dppf<0x1B>(h);           // h[j^3]
            const float h7 = dppf<0x141>(h); // h[j^7] (row_half_mirror)
            a[7] = h7;
            a[6] = dppf<0xB1>(h7);          // h[j^6]
            a[5] = dppf<0x4E>(h7);          // h[j^5]
            a[4] = dppf<0x1B>(h7);          // h[j^4]
        }
    }

    out[4194304 + bid * 64 + l] = h;   // hx
    out[4198400 + bid * 64 + l] = c;   // cx
}

// ---------------------------------------------------------------------------
extern "C" void kernel_launch(void* const* d_in, const int* in_sizes, int n_in,
                              void* d_out, int out_size, void* d_ws, size_t ws_size,
                              hipStream_t stream) {
    const float* x   = (const float*)d_in[0];
    const float* Wf  = (const float*)d_in[1];
    const float* bf  = (const float*)d_in[2];
    const float* Wi  = (const float*)d_in[3];
    const float* bi  = (const float*)d_in[4];
    const float* Wu  = (const float*)d_in[5];
    const float* bu  = (const float*)d_in[6];
    const float* Wo  = (const float*)d_in[7];
    const float* bo  = (const float*)d_in[8];
    const float* qwf = (const float*)d_in[9];
    const float* qwi = (const float*)d_in[10];
    // d_in[11] = qwu: unused (g-gate has no quantum circuit in the reference)
    const float* qwo = (const float*)d_in[12];
    float* out = (float*)d_out;
    float* Z   = (float*)d_ws;      // [1024][64][96] f32 = 25.2 MB

    qlstm_zx2<<<2048, 256, 0, stream>>>(x, Wf, bf, Wi, bi, Wu, bu, Wo, bo, Z);
    qlstm_rec2<<<64, 64, 0, stream>>>(Z, Wf, Wi, Wu, Wo, qwf, qwi, qwo, out);
}